// Round 5
// baseline (294.565 us; speedup 1.0000x reference)
//
#include <hip/hip_runtime.h>
#include <math.h>

// N=4, C=256, H=W=32, NH=2, HD=128, MAX_DIS=7, WS=15, WW=225, T=sqrt(128)
// out: [hw=1024][n=4][c=256] fp32

__device__ __forceinline__ int iclamp(int v, int lo, int hi) {
    return v < lo ? lo : (v > hi ? hi : v);
}

// ---------------------------------------------------------------------------
// Tiled fp32 GEMM body: Y(64x64 tile) = W[M,K] x X[K,1024], BK=32.
// flags: 2 = interleaved store (Y[(col)*ldI + storeOff + row]), 4 = atomicAdd.
// K multiple of 32. X/Y have 1024 columns.
// ---------------------------------------------------------------------------
__device__ __forceinline__
void gemm_body(const float* __restrict__ Wb, const float* __restrict__ Xb,
               const float* __restrict__ biasb, float* __restrict__ Yb,
               int M, int K, int kt0, int kt1, bool addBias, int flags,
               long storeOff, int ldI)
{
    __shared__ __align__(16) float sm[64 * 68];   // 17.4 KB
    float* Ws = sm;               // [32][68] k-major, d contiguous
    float* Xs = sm + 32 * 68;     // [32][64] k-major, m contiguous

    const int row0 = blockIdx.y * 64;
    const int col0 = blockIdx.x * 64;
    const int tid = threadIdx.x;
    const int tx = tid & 15, ty = tid >> 4;

    float acc[4][4];
#pragma unroll
    for (int i = 0; i < 4; ++i)
#pragma unroll
        for (int j = 0; j < 4; ++j) acc[i][j] = 0.f;

    for (int kt = kt0; kt < kt1; ++kt) {
        const int c0 = kt * 32;
#pragma unroll
        for (int i = 0; i < 2; ++i) {
            int e = tid + i * 256;
            int dd = e >> 3, c4 = (e & 7) * 4;
            int gd = row0 + dd;
            float4 w4 = make_float4(0.f, 0.f, 0.f, 0.f);
            if (gd < M) w4 = *(const float4*)&Wb[(long)gd * K + c0 + c4];
            Ws[(c4 + 0) * 68 + dd] = w4.x;
            Ws[(c4 + 1) * 68 + dd] = w4.y;
            Ws[(c4 + 2) * 68 + dd] = w4.z;
            Ws[(c4 + 3) * 68 + dd] = w4.w;
        }
#pragma unroll
        for (int i = 0; i < 2; ++i) {
            int e = tid + i * 256;
            int cc = e >> 4, m4 = (e & 15) * 4;
            float4 x4 = *(const float4*)&Xb[((long)(c0 + cc) << 10) + col0 + m4];
            *(float4*)&Xs[cc * 64 + m4] = x4;
        }
        __syncthreads();
#pragma unroll
        for (int k = 0; k < 32; ++k) {
            const float4 a4 = *(const float4*)&Ws[k * 68 + ty * 4];
            const float4 b4 = *(const float4*)&Xs[k * 64 + tx * 4];
            float av[4] = {a4.x, a4.y, a4.z, a4.w};
            float bv[4] = {b4.x, b4.y, b4.z, b4.w};
#pragma unroll
            for (int i = 0; i < 4; ++i)
#pragma unroll
                for (int j = 0; j < 4; ++j) acc[i][j] += av[i] * bv[j];
        }
        __syncthreads();
    }

    if (!(flags & 2)) {
#pragma unroll
        for (int i = 0; i < 4; ++i) {
            int gd = row0 + ty * 4 + i;
            if (gd >= M) continue;
            float bvv = (addBias && biasb) ? biasb[gd] : 0.f;
            long yoff = ((long)gd << 10) + col0 + tx * 4;
            if (flags & 4) {
#pragma unroll
                for (int j = 0; j < 4; ++j)
                    atomicAdd(&Yb[yoff + j], acc[i][j] + bvv);
            } else {
                float4 r;
                r.x = acc[i][0] + bvv; r.y = acc[i][1] + bvv;
                r.z = acc[i][2] + bvv; r.w = acc[i][3] + bvv;
                *(float4*)&Yb[yoff] = r;
            }
        }
    } else {
        float* tile = sm;  // [64 m][68 d]
#pragma unroll
        for (int i = 0; i < 4; ++i) {
            float bvv = (addBias && biasb) ? biasb[row0 + ty * 4 + i] : 0.f;
#pragma unroll
            for (int j = 0; j < 4; ++j)
                tile[(tx * 4 + j) * 68 + ty * 4 + i] = acc[i][j] + bvv;
        }
        __syncthreads();
#pragma unroll
        for (int it = 0; it < 16; ++it) {
            int e = tid + it * 256;
            int dd = e & 63, mm = e >> 6;
            long off = (long)(col0 + mm) * ldI + storeOff + row0 + dd;
            if (flags & 4) atomicAdd(&Yb[off], tile[mm * 68 + dd]);
            else Yb[off] = tile[mm * 68 + dd];
        }
    }
}

__global__ __launch_bounds__(256)
void gemm_kernel(const float* __restrict__ W, const float* __restrict__ X,
                 const float* __restrict__ bias, float* __restrict__ Y,
                 int M, int K, long wStride, int wMod,
                 long xStride, long yStride, int biasStride, int biasMod,
                 int flags, int kSplit, int ldI)
{
    int b = blockIdx.z / kSplit;
    int ks = blockIdx.z - b * kSplit;
    int ktiles = (K + 31) >> 5;
    int kt0 = ks * ktiles / kSplit, kt1 = (ks + 1) * ktiles / kSplit;
    const float* Wb = W + (long)(b % wMod) * wStride;
    const float* Xb = X + (long)b * xStride;
    const float* biasb = bias ? (bias + (long)(b % biasMod) * biasStride) : nullptr;
    float* Yb; long storeOff = 0;
    if (flags & 2) { Yb = Y; storeOff = (long)b * M; }
    else           { Yb = Y + (long)b * yStride; }
    gemm_body(Wb, Xb, biasb, Yb, M, K, kt0, kt1, ks == 0, flags, storeOff, ldI);
}

// Q,K,V projections fused into one dispatch: blockIdx.z = sel*4 + batch
__global__ __launch_bounds__(256)
void qkv_kernel(const float* __restrict__ q, const float* __restrict__ k,
                const float* __restrict__ v,
                const float* __restrict__ Wq, const float* __restrict__ Wk,
                const float* __restrict__ Wv,
                const float* __restrict__ bq, const float* __restrict__ bk,
                const float* __restrict__ bv,
                float* __restrict__ qp, float* __restrict__ kp,
                float* __restrict__ vp)
{
    int b = blockIdx.z;
    int sel = b >> 2, batch = b & 3;
    const float *W, *X, *bias; float* Y;
    if (sel == 0)      { W = Wq; X = q; bias = bq; Y = qp; }
    else if (sel == 1) { W = Wk; X = k; bias = bk; Y = kp; }
    else               { W = Wv; X = v; bias = bv; Y = vp; }
    gemm_body(W, X + ((long)batch << 18), bias, Y + ((long)batch << 18),
              256, 256, 0, 8, true, 0, 0, 0);
}

// ---------------------------------------------------------------------------
// scores + softmax: block = (y row, x-half, ng). grid (64,8) = 512 blocks.
// thread = (c-quarter, dy, x-quad): acc[4 px][15 dx], sliding K window of 20
// floats (5 aligned float4 per channel) -> 60 FMA per channel, 32 channels.
// cq0 writes (rel+mask), cq1..3 LDS-atomicAdd partials. Softmax in-block.
// LDS: qs 8 KB + qk 15.4 KB = ~23.5 KB -> 2 blocks/CU, 8 waves/CU.
// ---------------------------------------------------------------------------
__global__ __launch_bounds__(256)
void scores_kernel(const float* __restrict__ qp, const float* __restrict__ kp,
                   float* __restrict__ relattn)
{
    __shared__ __align__(16) float qs[128 * 16];   // [c][16 x], scaled by 1/T
    __shared__ float qk[16 * 241];                 // [px][15*16 + pad]
    __shared__ float invl[16];

    const int tid = threadIdx.x;
    const int y  = blockIdx.x >> 1;           // 0..31
    const int xh = blockIdx.x & 1;
    const int bz = blockIdx.y;                // n*2+g
    const long hoff = (long)((bz >> 1) * 256 + (bz & 1) * 128) << 10;
    const float* qh = qp + hoff;
    const float* kh = kp + hoff;
    float* relh = relattn + (long)bz * 230400;
    const float invT = 0.08838834764831845f;  // 1/sqrt(128)
    const int xbase = xh * 16;

    // stage q: [128 c][16 x]
    for (int e = tid; e < 2048; e += 256) {
        int c = e >> 4, x = e & 15;
        qs[e] = qh[((long)c << 10) + y * 32 + xbase + x] * invT;
    }
    __syncthreads();

    const int cq = tid >> 6;          // c-quarter 0..3 (32 ch each)
    const int r  = tid & 63;
    const int dy = r >> 2;            // 0..15 (15 inactive)
    const int xq = r & 3;
    const int x0l = xq * 4;           // local px base
    const int x0g = xbase + x0l;      // global px base
    const bool active = (dy < 15);
    const int ky = y + dy - 7;        // may be out of [0,32): unclamped read,
                                      // memory-safe inside ws, masked below
    float acc[4][15];
#pragma unroll
    for (int i = 0; i < 4; ++i)
#pragma unroll
        for (int dx = 0; dx < 15; ++dx) acc[i][dx] = 0.f;

    if (active) {
        const float* kr = kh + (long)ky * 32 + (x0g - 8);   // 16B-aligned
        const int cbase = cq * 32;
#pragma unroll 2
        for (int cc = 0; cc < 32; ++cc) {
            const int c = cbase + cc;
            const float4* p4 = (const float4*)(kr + ((long)c << 10));
            float4 w0 = p4[0], w1 = p4[1], w2 = p4[2], w3 = p4[3], w4 = p4[4];
            float w[20] = {w0.x, w0.y, w0.z, w0.w, w1.x, w1.y, w1.z, w1.w,
                           w2.x, w2.y, w2.z, w2.w, w3.x, w3.y, w3.z, w3.w,
                           w4.x, w4.y, w4.z, w4.w};
            const float4 q4 = *(const float4*)&qs[c * 16 + x0l];
            float qa[4] = {q4.x, q4.y, q4.z, q4.w};
#pragma unroll
            for (int i = 0; i < 4; ++i)
#pragma unroll
                for (int dx = 0; dx < 15; ++dx)
                    acc[i][dx] += qa[i] * w[i + dx + 1];
        }
    }

    const bool vy = (ky >= 0) && (ky < 32);
    if (cq == 0 && active) {
#pragma unroll
        for (int i = 0; i < 4; ++i) {
            int px = x0l + i, m = y * 32 + x0g + i;
#pragma unroll
            for (int dx = 0; dx < 15; ++dx) {
                int hx = x0g + i + dx - 7;
                float val = -1e8f;
                if (vy && hx >= 0 && hx < 32)
                    val = acc[i][dx] + relh[((long)(dy * 15 + dx) << 10) + m];
                qk[px * 241 + dy * 16 + dx] = val;
            }
            qk[px * 241 + dy * 16 + 15] = -1e8f;   // pad slot
        }
    }
    __syncthreads();
    if (cq != 0 && active) {
#pragma unroll
        for (int i = 0; i < 4; ++i) {
            int px = x0l + i;
#pragma unroll
            for (int dx = 0; dx < 15; ++dx) {
                int hx = x0g + i + dx - 7;
                if (vy && hx >= 0 && hx < 32)
                    atomicAdd(&qk[px * 241 + dy * 16 + dx], acc[i][dx]);
            }
        }
    }
    __syncthreads();

    // softmax over 240 slots: 16 threads per px
    {
        int px = tid >> 4, s = tid & 15;
        float mx = -3.0e38f;
        for (int w = s; w < 240; w += 16) mx = fmaxf(mx, qk[px * 241 + w]);
#pragma unroll
        for (int msk = 8; msk; msk >>= 1) mx = fmaxf(mx, __shfl_xor(mx, msk));
        float sum = 0.f;
        for (int w = s; w < 240; w += 16) {
            float p = __expf(qk[px * 241 + w] - mx);
            qk[px * 241 + w] = p;
            sum += p;
        }
#pragma unroll
        for (int msk = 8; msk; msk >>= 1) sum += __shfl_xor(sum, msk);
        if (s == 0) invl[px] = 1.0f / sum;
    }
    __syncthreads();

    // write normalized attention back: 16 contiguous px per w
    for (int e = tid; e < 3600; e += 256) {
        int px = e & 15, w = e >> 4;      // w in 0..224
        int dy2 = w / 15, dx2 = w - dy2 * 15;
        relh[((long)w << 10) + y * 32 + xbase + px] =
            qk[px * 241 + dy2 * 16 + dx2] * invl[px];
    }
}

// ---------------------------------------------------------------------------
// PV gather + V_bias fold: agg[c][m] = sum_w p[w][m]*(Vgather[c][w][m]+Vb[c][w])
// grid (cgrp 32, ytile 4, ng 8) = 1024 blocks -> 4 blocks/CU, 16 waves/CU.
// thread = (cs channel, y in 8, x-quad): 1 channel x 4 px, sliding V window.
// ---------------------------------------------------------------------------
__global__ __launch_bounds__(256)
void pv_kernel(const float* __restrict__ vp, const float* __restrict__ attn,
               const float* __restrict__ Vbias, float* __restrict__ agg)
{
    __shared__ float vbs[4 * 225];
    const int tid = threadIdx.x;
    const int cgrp = blockIdx.x;        // 0..31
    const int yt = blockIdx.y;          // 0..3
    const int bz = blockIdx.z;          // n*2+g
    const int n = bz >> 1, g = bz & 1;
    const int c0 = cgrp * 4;            // channel base within head

    for (int e = tid; e < 900; e += 256) {
        int j = e / 225, w = e - j * 225;
        vbs[j * 225 + w] = Vbias[(g * 128 + c0 + j) * 225 + w];
    }
    __syncthreads();

    const int cs = tid >> 6;            // 0..3: this thread's channel
    const int r  = tid & 63;
    const int y  = yt * 8 + (r >> 3);
    const int x0 = (r & 7) * 4;
    const int m  = y * 32 + x0;
    const float* ah = attn + (long)bz * 230400 + m;
    const float* vb = vp + ((long)(n * 256 + g * 128 + c0 + cs) << 10);
    const float* vbc = &vbs[cs * 225];
    const int hx0 = x0 - 7;

    float a0 = 0.f, a1 = 0.f, a2 = 0.f, a3 = 0.f;
    for (int dy = 0; dy < 15; ++dy) {
        int hy = y + dy - 7;
        if (hy < 0 || hy > 31) continue;          // all p == 0 for this dy
        const float* vrow = vb + hy * 32;
        float w0 = vrow[iclamp(hx0 + 0, 0, 31)];
        float w1 = vrow[iclamp(hx0 + 1, 0, 31)];
        float w2 = vrow[iclamp(hx0 + 2, 0, 31)];
        float w3 = vrow[iclamp(hx0 + 3, 0, 31)];
        const float* arow = ah + (long)(dy * 15) * 1024;
        const float* vbrow = vbc + dy * 15;
#pragma unroll
        for (int dx = 0; dx < 15; ++dx) {
            float4 p4 = *(const float4*)&arow[(long)dx << 10];
            float vbj = vbrow[dx];
            a0 += p4.x * (w0 + vbj);
            a1 += p4.y * (w1 + vbj);
            a2 += p4.z * (w2 + vbj);
            a3 += p4.w * (w3 + vbj);
            if (dx < 14) {
                w0 = w1; w1 = w2; w2 = w3;
                w3 = vrow[iclamp(hx0 + dx + 4, 0, 31)];
            }
        }
    }

    float* ag = agg + ((long)n << 18) + ((long)(g * 128 + c0 + cs) << 10) + m;
    *(float4*)ag = make_float4(a0, a1, a2, a3);
}

// ---------------------------------------------------------------------------
// ws floats: qp[1048576] kp[1048576] vp[1048576] rel/attn[1843200] agg[1048576]
// ---------------------------------------------------------------------------
extern "C" void kernel_launch(void* const* d_in, const int* in_sizes, int n_in,
                              void* d_out, int out_size, void* d_ws, size_t ws_size,
                              hipStream_t stream)
{
    const float* q    = (const float*)d_in[0];
    const float* k    = (const float*)d_in[1];
    const float* v    = (const float*)d_in[2];
    const float* Wq   = (const float*)d_in[3];
    const float* bq   = (const float*)d_in[4];
    const float* Wk   = (const float*)d_in[5];
    const float* bk   = (const float*)d_in[6];
    const float* Wv   = (const float*)d_in[7];
    const float* bv   = (const float*)d_in[8];
    const float* Wrel = (const float*)d_in[9];
    const float* brel = (const float*)d_in[10];
    const float* Vb   = (const float*)d_in[11];
    const float* Wfc  = (const float*)d_in[12];
    const float* bfc  = (const float*)d_in[13];
    float* out = (float*)d_out;

    float* ws  = (float*)d_ws;
    float* qp  = ws;
    float* kp  = ws + 1048576;
    float* vp  = ws + 2097152;
    float* rel = ws + 3145728;      // 8*225*1024, becomes attn in place
    float* agg = ws + 4988928;      // [n][256][1024]

    dim3 blk(256);

    // FC uses split-K atomics -> zero out (capture-safe memset node)
    hipMemsetAsync(out, 0, (size_t)out_size * 4, stream);

    // fused QKV projections: 16*4*12 = 768 blocks, direct store
    qkv_kernel<<<dim3(16, 4, 12), blk, 0, stream>>>(q, k, v, Wq, Wk, Wv,
                                                    bq, bk, bv, qp, kp, vp);

    // rel logits: 16*4*8 = 512 blocks, direct store
    gemm_kernel<<<dim3(16, 4, 8), blk, 0, stream>>>(Wrel, qp, brel, rel,
        225, 128, 28800, 2, 131072, 230400, 225, 2, 0, 1, 0);

    // scores + softmax -> attn (in place over rel): 512 blocks
    scores_kernel<<<dim3(64, 8), blk, 0, stream>>>(qp, kp, rel);

    // PV gather + V_bias fold -> agg: 1024 blocks
    pv_kernel<<<dim3(32, 4, 8), blk, 0, stream>>>(vp, rel, Vb, agg);

    // FC with interleaved [m][n][c] store, split-K=2: 16*4*8 = 512 blocks
    gemm_kernel<<<dim3(16, 4, 8), blk, 0, stream>>>(Wfc, agg, bfc, out,
        256, 256, 0, 1, 262144, 0, 0, 1, 6, 2, 1024);
}

// Round 6
// 255.174 us; speedup vs baseline: 1.1544x; 1.1544x over previous
//
#include <hip/hip_runtime.h>
#include <math.h>

// N=4, C=256, H=W=32, NH=2, HD=128, MAX_DIS=7, WS=15, WW=225, T=sqrt(128)
// out: [hw=1024][n=4][c=256] fp32

__device__ __forceinline__ int iclamp(int v, int lo, int hi) {
    return v < lo ? lo : (v > hi ? hi : v);
}

// ---------------------------------------------------------------------------
// Tiled fp32 GEMM body: Y(64x64 tile) = W[M,K] x X[K,1024], BK=32.
// flags: 2 = interleaved store (Y[(col)*ldI + storeOff + row]), 4 = atomicAdd.
// K multiple of 32. X/Y have 1024 columns.
// ---------------------------------------------------------------------------
__device__ __forceinline__
void gemm_body(const float* __restrict__ Wb, const float* __restrict__ Xb,
               const float* __restrict__ biasb, float* __restrict__ Yb,
               int M, int K, int kt0, int kt1, bool addBias, int flags,
               long storeOff, int ldI)
{
    __shared__ __align__(16) float sm[64 * 68];   // 17.4 KB
    float* Ws = sm;               // [32][68] k-major, d contiguous
    float* Xs = sm + 32 * 68;     // [32][64] k-major, m contiguous

    const int row0 = blockIdx.y * 64;
    const int col0 = blockIdx.x * 64;
    const int tid = threadIdx.x;
    const int tx = tid & 15, ty = tid >> 4;

    float acc[4][4];
#pragma unroll
    for (int i = 0; i < 4; ++i)
#pragma unroll
        for (int j = 0; j < 4; ++j) acc[i][j] = 0.f;

    for (int kt = kt0; kt < kt1; ++kt) {
        const int c0 = kt * 32;
#pragma unroll
        for (int i = 0; i < 2; ++i) {
            int e = tid + i * 256;
            int dd = e >> 3, c4 = (e & 7) * 4;
            int gd = row0 + dd;
            float4 w4 = make_float4(0.f, 0.f, 0.f, 0.f);
            if (gd < M) w4 = *(const float4*)&Wb[(long)gd * K + c0 + c4];
            Ws[(c4 + 0) * 68 + dd] = w4.x;
            Ws[(c4 + 1) * 68 + dd] = w4.y;
            Ws[(c4 + 2) * 68 + dd] = w4.z;
            Ws[(c4 + 3) * 68 + dd] = w4.w;
        }
#pragma unroll
        for (int i = 0; i < 2; ++i) {
            int e = tid + i * 256;
            int cc = e >> 4, m4 = (e & 15) * 4;
            float4 x4 = *(const float4*)&Xb[((long)(c0 + cc) << 10) + col0 + m4];
            *(float4*)&Xs[cc * 64 + m4] = x4;
        }
        __syncthreads();
#pragma unroll
        for (int k = 0; k < 32; ++k) {
            const float4 a4 = *(const float4*)&Ws[k * 68 + ty * 4];
            const float4 b4 = *(const float4*)&Xs[k * 64 + tx * 4];
            float av[4] = {a4.x, a4.y, a4.z, a4.w};
            float bv[4] = {b4.x, b4.y, b4.z, b4.w};
#pragma unroll
            for (int i = 0; i < 4; ++i)
#pragma unroll
                for (int j = 0; j < 4; ++j) acc[i][j] += av[i] * bv[j];
        }
        __syncthreads();
    }

    if (!(flags & 2)) {
#pragma unroll
        for (int i = 0; i < 4; ++i) {
            int gd = row0 + ty * 4 + i;
            if (gd >= M) continue;
            float bvv = (addBias && biasb) ? biasb[gd] : 0.f;
            long yoff = ((long)gd << 10) + col0 + tx * 4;
            if (flags & 4) {
#pragma unroll
                for (int j = 0; j < 4; ++j)
                    atomicAdd(&Yb[yoff + j], acc[i][j] + bvv);
            } else {
                float4 r;
                r.x = acc[i][0] + bvv; r.y = acc[i][1] + bvv;
                r.z = acc[i][2] + bvv; r.w = acc[i][3] + bvv;
                *(float4*)&Yb[yoff] = r;
            }
        }
    } else {
        float* tile = sm;  // [64 m][68 d]
#pragma unroll
        for (int i = 0; i < 4; ++i) {
            float bvv = (addBias && biasb) ? biasb[row0 + ty * 4 + i] : 0.f;
#pragma unroll
            for (int j = 0; j < 4; ++j)
                tile[(tx * 4 + j) * 68 + ty * 4 + i] = acc[i][j] + bvv;
        }
        __syncthreads();
#pragma unroll
        for (int it = 0; it < 16; ++it) {
            int e = tid + it * 256;
            int dd = e & 63, mm = e >> 6;
            long off = (long)(col0 + mm) * ldI + storeOff + row0 + dd;
            if (flags & 4) atomicAdd(&Yb[off], tile[mm * 68 + dd]);
            else Yb[off] = tile[mm * 68 + dd];
        }
    }
}

__global__ __launch_bounds__(256)
void gemm_kernel(const float* __restrict__ W, const float* __restrict__ X,
                 const float* __restrict__ bias, float* __restrict__ Y,
                 int M, int K, long wStride, int wMod,
                 long xStride, long yStride, int biasStride, int biasMod,
                 int flags, int kSplit, int ldI)
{
    int b = blockIdx.z / kSplit;
    int ks = blockIdx.z - b * kSplit;
    int ktiles = (K + 31) >> 5;
    int kt0 = ks * ktiles / kSplit, kt1 = (ks + 1) * ktiles / kSplit;
    const float* Wb = W + (long)(b % wMod) * wStride;
    const float* Xb = X + (long)b * xStride;
    const float* biasb = bias ? (bias + (long)(b % biasMod) * biasStride) : nullptr;
    float* Yb; long storeOff = 0;
    if (flags & 2) { Yb = Y; storeOff = (long)b * M; }
    else           { Yb = Y + (long)b * yStride; }
    gemm_body(Wb, Xb, biasb, Yb, M, K, kt0, kt1, ks == 0, flags, storeOff, ldI);
}

// Q,K,V projections fused into one dispatch: blockIdx.z = sel*4 + batch
__global__ __launch_bounds__(256)
void qkv_kernel(const float* __restrict__ q, const float* __restrict__ k,
                const float* __restrict__ v,
                const float* __restrict__ Wq, const float* __restrict__ Wk,
                const float* __restrict__ Wv,
                const float* __restrict__ bq, const float* __restrict__ bk,
                const float* __restrict__ bv,
                float* __restrict__ qp, float* __restrict__ kp,
                float* __restrict__ vp)
{
    int b = blockIdx.z;
    int sel = b >> 2, batch = b & 3;
    const float *W, *X, *bias; float* Y;
    if (sel == 0)      { W = Wq; X = q; bias = bq; Y = qp; }
    else if (sel == 1) { W = Wk; X = k; bias = bk; Y = kp; }
    else               { W = Wv; X = v; bias = bv; Y = vp; }
    gemm_body(W, X + ((long)batch << 18), bias, Y + ((long)batch << 18),
              256, 256, 0, 8, true, 0, 0, 0);
}

// ---------------------------------------------------------------------------
// scores + softmax: block = (y row, x-half, ng). grid (64,8) = 512 blocks.
// thread = (c-quarter, dy, x-quad): acc[4 px][15 dx], sliding K window of 20
// floats (5 aligned float4 per channel) -> 60 FMA per channel, 32 channels.
// cq0 writes (rel+mask), cq1..3 LDS-atomicAdd partials. Softmax in-block.
// ---------------------------------------------------------------------------
__global__ __launch_bounds__(256)
void scores_kernel(const float* __restrict__ qp, const float* __restrict__ kp,
                   float* __restrict__ relattn)
{
    __shared__ __align__(16) float qs[128 * 16];   // [c][16 x], scaled by 1/T
    __shared__ float qk[16 * 241];                 // [px][15*16 + pad]
    __shared__ float invl[16];

    const int tid = threadIdx.x;
    const int y  = blockIdx.x >> 1;           // 0..31
    const int xh = blockIdx.x & 1;
    const int bz = blockIdx.y;                // n*2+g
    const long hoff = (long)((bz >> 1) * 256 + (bz & 1) * 128) << 10;
    const float* qh = qp + hoff;
    const float* kh = kp + hoff;
    float* relh = relattn + (long)bz * 230400;
    const float invT = 0.08838834764831845f;  // 1/sqrt(128)
    const int xbase = xh * 16;

    for (int e = tid; e < 2048; e += 256) {
        int c = e >> 4, x = e & 15;
        qs[e] = qh[((long)c << 10) + y * 32 + xbase + x] * invT;
    }
    __syncthreads();

    const int cq = tid >> 6;          // c-quarter 0..3 (32 ch each)
    const int r  = tid & 63;
    const int dy = r >> 2;            // 0..15 (15 inactive)
    const int xq = r & 3;
    const int x0l = xq * 4;           // local px base
    const int x0g = xbase + x0l;      // global px base
    const bool active = (dy < 15);
    const int ky = y + dy - 7;        // may be out of [0,32): unclamped read,
                                      // memory-safe inside ws, masked below
    float acc[4][15];
#pragma unroll
    for (int i = 0; i < 4; ++i)
#pragma unroll
        for (int dx = 0; dx < 15; ++dx) acc[i][dx] = 0.f;

    if (active) {
        const float* kr = kh + (long)ky * 32 + (x0g - 8);   // 16B-aligned
        const int cbase = cq * 32;
#pragma unroll 2
        for (int cc = 0; cc < 32; ++cc) {
            const int c = cbase + cc;
            const float4* p4 = (const float4*)(kr + ((long)c << 10));
            float4 w0 = p4[0], w1 = p4[1], w2 = p4[2], w3 = p4[3], w4 = p4[4];
            float w[20] = {w0.x, w0.y, w0.z, w0.w, w1.x, w1.y, w1.z, w1.w,
                           w2.x, w2.y, w2.z, w2.w, w3.x, w3.y, w3.z, w3.w,
                           w4.x, w4.y, w4.z, w4.w};
            const float4 q4 = *(const float4*)&qs[c * 16 + x0l];
            float qa[4] = {q4.x, q4.y, q4.z, q4.w};
#pragma unroll
            for (int i = 0; i < 4; ++i)
#pragma unroll
                for (int dx = 0; dx < 15; ++dx)
                    acc[i][dx] += qa[i] * w[i + dx + 1];
        }
    }

    const bool vy = (ky >= 0) && (ky < 32);
    if (cq == 0 && active) {
#pragma unroll
        for (int i = 0; i < 4; ++i) {
            int px = x0l + i, m = y * 32 + x0g + i;
#pragma unroll
            for (int dx = 0; dx < 15; ++dx) {
                int hx = x0g + i + dx - 7;
                float val = -1e8f;
                if (vy && hx >= 0 && hx < 32)
                    val = acc[i][dx] + relh[((long)(dy * 15 + dx) << 10) + m];
                qk[px * 241 + dy * 16 + dx] = val;
            }
            qk[px * 241 + dy * 16 + 15] = -1e8f;   // pad slot
        }
    }
    __syncthreads();
    if (cq != 0 && active) {
#pragma unroll
        for (int i = 0; i < 4; ++i) {
            int px = x0l + i;
#pragma unroll
            for (int dx = 0; dx < 15; ++dx) {
                int hx = x0g + i + dx - 7;
                if (vy && hx >= 0 && hx < 32)
                    atomicAdd(&qk[px * 241 + dy * 16 + dx], acc[i][dx]);
            }
        }
    }
    __syncthreads();

    // softmax over 240 slots: 16 threads per px
    {
        int px = tid >> 4, s = tid & 15;
        float mx = -3.0e38f;
        for (int w = s; w < 240; w += 16) mx = fmaxf(mx, qk[px * 241 + w]);
#pragma unroll
        for (int msk = 8; msk; msk >>= 1) mx = fmaxf(mx, __shfl_xor(mx, msk));
        float sum = 0.f;
        for (int w = s; w < 240; w += 16) {
            float p = __expf(qk[px * 241 + w] - mx);
            qk[px * 241 + w] = p;
            sum += p;
        }
#pragma unroll
        for (int msk = 8; msk; msk >>= 1) sum += __shfl_xor(sum, msk);
        if (s == 0) invl[px] = 1.0f / sum;
    }
    __syncthreads();

    for (int e = tid; e < 3600; e += 256) {
        int px = e & 15, w = e >> 4;      // w in 0..224
        int dy2 = w / 15, dx2 = w - dy2 * 15;
        relh[((long)w << 10) + y * 32 + xbase + px] =
            qk[px * 241 + dy2 * 16 + dx2] * invl[px];
    }
}

// ---------------------------------------------------------------------------
// PV gather + V_bias fold, LDS-staged attn:
//   agg[c][m] = sum_w p[w][m]*(Vgather[c][w][m]+Vb[c][w])
// grid (y 32, ch-half 2, ng 8) = 512 blocks; 256 thr = (32 chg x 8 xq);
// thread = 2 channels x 4 px. attn row tile [225 w][32 px] staged in LDS
// (28.8 KB) -> read once from global per (block), b128 broadcast reads.
// ---------------------------------------------------------------------------
__global__ __launch_bounds__(256)
void pv_kernel(const float* __restrict__ vp, const float* __restrict__ attn,
               const float* __restrict__ Vbias, float* __restrict__ agg)
{
    __shared__ __align__(16) float pa[225 * 32];   // [w][px] 28.8 KB
    const int tid = threadIdx.x;
    const int y   = blockIdx.x;        // 0..31
    const int chh = blockIdx.y;        // 0..1
    const int bz  = blockIdx.z;        // n*2+g
    const int n = bz >> 1, g = bz & 1;

    const float* ab = attn + (long)bz * 230400 + y * 32;
    for (int e = tid; e < 1800; e += 256) {
        int w = e >> 3, x4 = (e & 7) * 4;
        *(float4*)&pa[w * 32 + x4] = *(const float4*)&ab[((long)w << 10) + x4];
    }
    __syncthreads();

    const int chg = tid >> 3;                 // 0..31
    const int xq  = tid & 7;
    const int c0  = chh * 64 + chg * 2;       // channel base within head
    const int x0  = xq * 4;
    const float* v0 = vp + ((long)(n * 256 + g * 128 + c0) << 10);
    const float* v1 = v0 + 1024;
    const float* b0 = Vbias + (g * 128 + c0) * 225;
    const float* b1 = b0 + 225;
    const int hx0 = x0 - 7;

    float acc0[4] = {0.f, 0.f, 0.f, 0.f};
    float acc1[4] = {0.f, 0.f, 0.f, 0.f};

    for (int dy = 0; dy < 15; ++dy) {
        int hy = y + dy - 7;
        if (hy < 0 || hy > 31) continue;       // all p == 0 for this dy
        const float* r0 = v0 + hy * 32;
        const float* r1 = v1 + hy * 32;
        float w0[4], w1[4];
#pragma unroll
        for (int t = 0; t < 4; ++t) {
            int hx = iclamp(hx0 + t, 0, 31);
            w0[t] = r0[hx]; w1[t] = r1[hx];
        }
        const float* par = &pa[dy * 15 * 32 + x0];
        const float* vb0 = b0 + dy * 15;
        const float* vb1 = b1 + dy * 15;
#pragma unroll
        for (int dx = 0; dx < 15; ++dx) {
            float4 p4 = *(const float4*)&par[dx * 32];
            float ba = vb0[dx], bb = vb1[dx];
            acc0[0] += p4.x * (w0[0] + ba);
            acc0[1] += p4.y * (w0[1] + ba);
            acc0[2] += p4.z * (w0[2] + ba);
            acc0[3] += p4.w * (w0[3] + ba);
            acc1[0] += p4.x * (w1[0] + bb);
            acc1[1] += p4.y * (w1[1] + bb);
            acc1[2] += p4.z * (w1[2] + bb);
            acc1[3] += p4.w * (w1[3] + bb);
            if (dx < 14) {
                int hx = iclamp(hx0 + dx + 4, 0, 31);
                w0[0] = w0[1]; w0[1] = w0[2]; w0[2] = w0[3]; w0[3] = r0[hx];
                w1[0] = w1[1]; w1[1] = w1[2]; w1[2] = w1[3]; w1[3] = r1[hx];
            }
        }
    }

    float* ag = agg + ((long)n << 18) + ((long)(g * 128 + c0) << 10) + y * 32 + x0;
    *(float4*)ag = make_float4(acc0[0], acc0[1], acc0[2], acc0[3]);
    *(float4*)(ag + 1024) = make_float4(acc1[0], acc1[1], acc1[2], acc1[3]);
}

// ---------------------------------------------------------------------------
// ws floats: qp[1048576] kp[1048576] vp[1048576] rel/attn[1843200] agg[1048576]
// ---------------------------------------------------------------------------
extern "C" void kernel_launch(void* const* d_in, const int* in_sizes, int n_in,
                              void* d_out, int out_size, void* d_ws, size_t ws_size,
                              hipStream_t stream)
{
    const float* q    = (const float*)d_in[0];
    const float* k    = (const float*)d_in[1];
    const float* v    = (const float*)d_in[2];
    const float* Wq   = (const float*)d_in[3];
    const float* bq   = (const float*)d_in[4];
    const float* Wk   = (const float*)d_in[5];
    const float* bk   = (const float*)d_in[6];
    const float* Wv   = (const float*)d_in[7];
    const float* bv   = (const float*)d_in[8];
    const float* Wrel = (const float*)d_in[9];
    const float* brel = (const float*)d_in[10];
    const float* Vb   = (const float*)d_in[11];
    const float* Wfc  = (const float*)d_in[12];
    const float* bfc  = (const float*)d_in[13];
    float* out = (float*)d_out;

    float* ws  = (float*)d_ws;
    float* qp  = ws;
    float* kp  = ws + 1048576;
    float* vp  = ws + 2097152;
    float* rel = ws + 3145728;      // 8*225*1024, becomes attn in place
    float* agg = ws + 4988928;      // [n][256][1024]

    dim3 blk(256);

    // FC uses split-K atomics -> zero out (capture-safe memset node)
    hipMemsetAsync(out, 0, (size_t)out_size * 4, stream);

    // fused QKV projections: 16*4*12 = 768 blocks, direct store
    qkv_kernel<<<dim3(16, 4, 12), blk, 0, stream>>>(q, k, v, Wq, Wk, Wv,
                                                    bq, bk, bv, qp, kp, vp);

    // rel logits: 16*4*8 = 512 blocks, direct store
    gemm_kernel<<<dim3(16, 4, 8), blk, 0, stream>>>(Wrel, qp, brel, rel,
        225, 128, 28800, 2, 131072, 230400, 225, 2, 0, 1, 0);

    // scores + softmax -> attn (in place over rel): 512 blocks
    scores_kernel<<<dim3(64, 8), blk, 0, stream>>>(qp, kp, rel);

    // PV gather + V_bias fold -> agg: 512 blocks, LDS-staged attn
    pv_kernel<<<dim3(32, 2, 8), blk, 0, stream>>>(vp, rel, Vb, agg);

    // FC with interleaved [m][n][c] store, split-K=2: 16*4*8 = 512 blocks
    gemm_kernel<<<dim3(16, 4, 8), blk, 0, stream>>>(Wfc, agg, bfc, out,
        256, 256, 0, 1, 262144, 0, 0, 1, 6, 2, 1024);
}

// Round 7
// 238.092 us; speedup vs baseline: 1.2372x; 1.0717x over previous
//
#include <hip/hip_runtime.h>
#include <math.h>

// N=4, C=256, H=W=32, NH=2, HD=128, MAX_DIS=7, WS=15, WW=225, T=sqrt(128)
// out: [hw=1024][n=4][c=256] fp32

__device__ __forceinline__ int iclamp(int v, int lo, int hi) {
    return v < lo ? lo : (v > hi ? hi : v);
}

// ---------------------------------------------------------------------------
// Tiled fp32 GEMM body: Y(64x64 tile) = W[M,K] x X[K,1024], BK=32.
// flags: 2 = interleaved store (Y[(col)*ldI + storeOff + row]), 4 = atomicAdd,
//        8 = padded-V store (Y[gd*1536 + row*48 + col + 8], row=m>>5,col=m&31)
// K multiple of 32. X has 1024 columns.
// ---------------------------------------------------------------------------
__device__ __forceinline__
void gemm_body(const float* __restrict__ Wb, const float* __restrict__ Xb,
               const float* __restrict__ biasb, float* __restrict__ Yb,
               int M, int K, int kt0, int kt1, bool addBias, int flags,
               long storeOff, int ldI)
{
    __shared__ __align__(16) float sm[64 * 68];   // 17.4 KB
    float* Ws = sm;               // [32][68] k-major, d contiguous
    float* Xs = sm + 32 * 68;     // [32][64] k-major, m contiguous

    const int row0 = blockIdx.y * 64;
    const int col0 = blockIdx.x * 64;
    const int tid = threadIdx.x;
    const int tx = tid & 15, ty = tid >> 4;

    float acc[4][4];
#pragma unroll
    for (int i = 0; i < 4; ++i)
#pragma unroll
        for (int j = 0; j < 4; ++j) acc[i][j] = 0.f;

    for (int kt = kt0; kt < kt1; ++kt) {
        const int c0 = kt * 32;
#pragma unroll
        for (int i = 0; i < 2; ++i) {
            int e = tid + i * 256;
            int dd = e >> 3, c4 = (e & 7) * 4;
            int gd = row0 + dd;
            float4 w4 = make_float4(0.f, 0.f, 0.f, 0.f);
            if (gd < M) w4 = *(const float4*)&Wb[(long)gd * K + c0 + c4];
            Ws[(c4 + 0) * 68 + dd] = w4.x;
            Ws[(c4 + 1) * 68 + dd] = w4.y;
            Ws[(c4 + 2) * 68 + dd] = w4.z;
            Ws[(c4 + 3) * 68 + dd] = w4.w;
        }
#pragma unroll
        for (int i = 0; i < 2; ++i) {
            int e = tid + i * 256;
            int cc = e >> 4, m4 = (e & 15) * 4;
            float4 x4 = *(const float4*)&Xb[((long)(c0 + cc) << 10) + col0 + m4];
            *(float4*)&Xs[cc * 64 + m4] = x4;
        }
        __syncthreads();
#pragma unroll
        for (int k = 0; k < 32; ++k) {
            const float4 a4 = *(const float4*)&Ws[k * 68 + ty * 4];
            const float4 b4 = *(const float4*)&Xs[k * 64 + tx * 4];
            float av[4] = {a4.x, a4.y, a4.z, a4.w};
            float bv[4] = {b4.x, b4.y, b4.z, b4.w};
#pragma unroll
            for (int i = 0; i < 4; ++i)
#pragma unroll
                for (int j = 0; j < 4; ++j) acc[i][j] += av[i] * bv[j];
        }
        __syncthreads();
    }

    if (flags & 8) {
        // padded V store: m -> row*48 + col + 8, scalar stores (4B aligned)
        int m4 = col0 + tx * 4;
        int row = m4 >> 5, col = (m4 & 31) + 8;
#pragma unroll
        for (int i = 0; i < 4; ++i) {
            int gd = row0 + ty * 4 + i;
            float bvv = (addBias && biasb) ? biasb[gd] : 0.f;
            long off = (long)gd * 1536 + row * 48 + col;
            Yb[off + 0] = acc[i][0] + bvv;
            Yb[off + 1] = acc[i][1] + bvv;
            Yb[off + 2] = acc[i][2] + bvv;
            Yb[off + 3] = acc[i][3] + bvv;
        }
    } else if (!(flags & 2)) {
#pragma unroll
        for (int i = 0; i < 4; ++i) {
            int gd = row0 + ty * 4 + i;
            if (gd >= M) continue;
            float bvv = (addBias && biasb) ? biasb[gd] : 0.f;
            long yoff = ((long)gd << 10) + col0 + tx * 4;
            if (flags & 4) {
#pragma unroll
                for (int j = 0; j < 4; ++j)
                    atomicAdd(&Yb[yoff + j], acc[i][j] + bvv);
            } else {
                float4 r;
                r.x = acc[i][0] + bvv; r.y = acc[i][1] + bvv;
                r.z = acc[i][2] + bvv; r.w = acc[i][3] + bvv;
                *(float4*)&Yb[yoff] = r;
            }
        }
    } else {
        float* tile = sm;  // [64 m][68 d]
#pragma unroll
        for (int i = 0; i < 4; ++i) {
            float bvv = (addBias && biasb) ? biasb[row0 + ty * 4 + i] : 0.f;
#pragma unroll
            for (int j = 0; j < 4; ++j)
                tile[(tx * 4 + j) * 68 + ty * 4 + i] = acc[i][j] + bvv;
        }
        __syncthreads();
#pragma unroll
        for (int it = 0; it < 16; ++it) {
            int e = tid + it * 256;
            int dd = e & 63, mm = e >> 6;
            long off = (long)(col0 + mm) * ldI + storeOff + row0 + dd;
            if (flags & 4) atomicAdd(&Yb[off], tile[mm * 68 + dd]);
            else Yb[off] = tile[mm * 68 + dd];
        }
    }
}

__global__ __launch_bounds__(256)
void gemm_kernel(const float* __restrict__ W, const float* __restrict__ X,
                 const float* __restrict__ bias, float* __restrict__ Y,
                 int M, int K, long wStride, int wMod,
                 long xStride, long yStride, int biasStride, int biasMod,
                 int flags, int kSplit, int ldI)
{
    int b = blockIdx.z / kSplit;
    int ks = blockIdx.z - b * kSplit;
    int ktiles = (K + 31) >> 5;
    int kt0 = ks * ktiles / kSplit, kt1 = (ks + 1) * ktiles / kSplit;
    const float* Wb = W + (long)(b % wMod) * wStride;
    const float* Xb = X + (long)b * xStride;
    const float* biasb = bias ? (bias + (long)(b % biasMod) * biasStride) : nullptr;
    float* Yb; long storeOff = 0;
    if (flags & 2) { Yb = Y; storeOff = (long)b * M; }
    else           { Yb = Y + (long)b * yStride; }
    gemm_body(Wb, Xb, biasb, Yb, M, K, kt0, kt1, ks == 0, flags, storeOff, ldI);
}

// Q,K,V projections fused: blockIdx.z = sel*4 + batch. V goes to padded layout.
__global__ __launch_bounds__(256)
void qkv_kernel(const float* __restrict__ q, const float* __restrict__ k,
                const float* __restrict__ v,
                const float* __restrict__ Wq, const float* __restrict__ Wk,
                const float* __restrict__ Wv,
                const float* __restrict__ bq, const float* __restrict__ bk,
                const float* __restrict__ bv,
                float* __restrict__ qp, float* __restrict__ kp,
                float* __restrict__ vpad)
{
    int b = blockIdx.z;
    int sel = b >> 2, batch = b & 3;
    if (sel == 2) {
        // V: padded store. channel gd in [0,256): off = gd*1536 + row*48+col+8
        gemm_body(Wv, v + ((long)batch << 18), bv, vpad + (long)batch * 393216,
                  256, 256, 0, 8, true, 8, 0, 0);
    } else {
        const float *W, *X, *bias; float* Y;
        if (sel == 0) { W = Wq; X = q; bias = bq; Y = qp; }
        else          { W = Wk; X = k; bias = bk; Y = kp; }
        gemm_body(W, X + ((long)batch << 18), bias, Y + ((long)batch << 18),
                  256, 256, 0, 8, true, 0, 0, 0);
    }
}

// ---------------------------------------------------------------------------
// scores + softmax: block = (y row, x-half, ng). grid (64,8) = 512 blocks.
// (unchanged from round 5)
// ---------------------------------------------------------------------------
__global__ __launch_bounds__(256)
void scores_kernel(const float* __restrict__ qp, const float* __restrict__ kp,
                   float* __restrict__ relattn)
{
    __shared__ __align__(16) float qs[128 * 16];   // [c][16 x], scaled by 1/T
    __shared__ float qk[16 * 241];                 // [px][15*16 + pad]
    __shared__ float invl[16];

    const int tid = threadIdx.x;
    const int y  = blockIdx.x >> 1;           // 0..31
    const int xh = blockIdx.x & 1;
    const int bz = blockIdx.y;                // n*2+g
    const long hoff = (long)((bz >> 1) * 256 + (bz & 1) * 128) << 10;
    const float* qh = qp + hoff;
    const float* kh = kp + hoff;
    float* relh = relattn + (long)bz * 230400;
    const float invT = 0.08838834764831845f;  // 1/sqrt(128)
    const int xbase = xh * 16;

    for (int e = tid; e < 2048; e += 256) {
        int c = e >> 4, x = e & 15;
        qs[e] = qh[((long)c << 10) + y * 32 + xbase + x] * invT;
    }
    __syncthreads();

    const int cq = tid >> 6;          // c-quarter 0..3 (32 ch each)
    const int r  = tid & 63;
    const int dy = r >> 2;            // 0..15 (15 inactive)
    const int xq = r & 3;
    const int x0l = xq * 4;           // local px base
    const int x0g = xbase + x0l;      // global px base
    const bool active = (dy < 15);
    const int ky = y + dy - 7;        // unclamped read, memory-safe inside ws

    float acc[4][15];
#pragma unroll
    for (int i = 0; i < 4; ++i)
#pragma unroll
        for (int dx = 0; dx < 15; ++dx) acc[i][dx] = 0.f;

    if (active) {
        const float* kr = kh + (long)ky * 32 + (x0g - 8);   // 16B-aligned
        const int cbase = cq * 32;
#pragma unroll 2
        for (int cc = 0; cc < 32; ++cc) {
            const int c = cbase + cc;
            const float4* p4 = (const float4*)(kr + ((long)c << 10));
            float4 w0 = p4[0], w1 = p4[1], w2 = p4[2], w3 = p4[3], w4 = p4[4];
            float w[20] = {w0.x, w0.y, w0.z, w0.w, w1.x, w1.y, w1.z, w1.w,
                           w2.x, w2.y, w2.z, w2.w, w3.x, w3.y, w3.z, w3.w,
                           w4.x, w4.y, w4.z, w4.w};
            const float4 q4 = *(const float4*)&qs[c * 16 + x0l];
            float qa[4] = {q4.x, q4.y, q4.z, q4.w};
#pragma unroll
            for (int i = 0; i < 4; ++i)
#pragma unroll
                for (int dx = 0; dx < 15; ++dx)
                    acc[i][dx] += qa[i] * w[i + dx + 1];
        }
    }

    const bool vy = (ky >= 0) && (ky < 32);
    if (cq == 0 && active) {
#pragma unroll
        for (int i = 0; i < 4; ++i) {
            int px = x0l + i, m = y * 32 + x0g + i;
#pragma unroll
            for (int dx = 0; dx < 15; ++dx) {
                int hx = x0g + i + dx - 7;
                float val = -1e8f;
                if (vy && hx >= 0 && hx < 32)
                    val = acc[i][dx] + relh[((long)(dy * 15 + dx) << 10) + m];
                qk[px * 241 + dy * 16 + dx] = val;
            }
            qk[px * 241 + dy * 16 + 15] = -1e8f;   // pad slot
        }
    }
    __syncthreads();
    if (cq != 0 && active) {
#pragma unroll
        for (int i = 0; i < 4; ++i) {
            int px = x0l + i;
#pragma unroll
            for (int dx = 0; dx < 15; ++dx) {
                int hx = x0g + i + dx - 7;
                if (vy && hx >= 0 && hx < 32)
                    atomicAdd(&qk[px * 241 + dy * 16 + dx], acc[i][dx]);
            }
        }
    }
    __syncthreads();

    {
        int px = tid >> 4, s = tid & 15;
        float mx = -3.0e38f;
        for (int w = s; w < 240; w += 16) mx = fmaxf(mx, qk[px * 241 + w]);
#pragma unroll
        for (int msk = 8; msk; msk >>= 1) mx = fmaxf(mx, __shfl_xor(mx, msk));
        float sum = 0.f;
        for (int w = s; w < 240; w += 16) {
            float p = __expf(qk[px * 241 + w] - mx);
            qk[px * 241 + w] = p;
            sum += p;
        }
#pragma unroll
        for (int msk = 8; msk; msk >>= 1) sum += __shfl_xor(sum, msk);
        if (s == 0) invl[px] = 1.0f / sum;
    }
    __syncthreads();

    for (int e = tid; e < 3600; e += 256) {
        int px = e & 15, w = e >> 4;      // w in 0..224
        int dy2 = w / 15, dx2 = w - dy2 * 15;
        relh[((long)w << 10) + y * 32 + xbase + px] =
            qk[px * 241 + dy2 * 16 + dx2] * invl[px];
    }
}

// ---------------------------------------------------------------------------
// PV v4: padded V, register window, dy-half split.
// grid (y 32, chh*dyh 4, bz 8) = 1024 blocks; thread = 2 ch x 4 px.
// Per (dy, ch): 5 aligned float4 V loads -> 20-float register window,
// inner dx loop statically indexed. attn tile [<=120 w][32 px] in LDS.
// Output via atomicAdd into zeroed agg (two dy-halves per address).
// ---------------------------------------------------------------------------
__global__ __launch_bounds__(256)
void pv_kernel(const float* __restrict__ vpad, const float* __restrict__ attn,
               const float* __restrict__ Vbias, float* __restrict__ agg)
{
    __shared__ __align__(16) float pa[120 * 32];   // 15.36 KB
    const int tid = threadIdx.x;
    const int y   = blockIdx.x;          // 0..31
    const int chh = blockIdx.y & 1;      // channel half
    const int dyh = blockIdx.y >> 1;     // dy half
    const int bz  = blockIdx.z;          // n*2+g
    const int n = bz >> 1, g = bz & 1;

    const int dy0 = dyh * 8;
    const int ndy = dyh ? 7 : 8;
    const int w0  = dy0 * 15;
    const int nw  = ndy * 15;

    const float* ab = attn + (long)bz * 230400 + ((long)w0 << 10) + y * 32;
    for (int e = tid; e < nw * 8; e += 256) {
        int w = e >> 3, x4 = (e & 7) * 4;
        *(float4*)&pa[w * 32 + x4] = *(const float4*)&ab[((long)w << 10) + x4];
    }
    __syncthreads();

    const int chg = tid >> 3;            // 0..31 -> 2 channels each
    const int xq  = tid & 7;
    const int c0  = chh * 64 + chg * 2;  // channel base within head
    const int x0  = xq * 4;
    const float* v0 = vpad + (long)bz * 196608 + (long)c0 * 1536;
    const float* v1 = v0 + 1536;
    const float* b0 = Vbias + (g * 128 + c0) * 225 + w0;
    const float* b1 = b0 + 225;

    float acc0[4] = {0.f, 0.f, 0.f, 0.f};
    float acc1[4] = {0.f, 0.f, 0.f, 0.f};

    for (int d = 0; d < ndy; ++d) {
        int hy = y + dy0 + d - 7;
        if (hy < 0 || hy > 31) continue;           // p == 0 for this dy
        const float4* r0 = (const float4*)(v0 + hy * 48 + x0);
        const float4* r1 = (const float4*)(v1 + hy * 48 + x0);
        float wa[20], wb[20];
#pragma unroll
        for (int t = 0; t < 5; ++t) {
            float4 a = r0[t], b = r1[t];
            wa[4*t+0] = a.x; wa[4*t+1] = a.y; wa[4*t+2] = a.z; wa[4*t+3] = a.w;
            wb[4*t+0] = b.x; wb[4*t+1] = b.y; wb[4*t+2] = b.z; wb[4*t+3] = b.w;
        }
        const float* par = &pa[d * 15 * 32 + x0];
        const float* vb0 = b0 + d * 15;
        const float* vb1 = b1 + d * 15;
#pragma unroll
        for (int dx = 0; dx < 15; ++dx) {
            float4 p4 = *(const float4*)&par[dx * 32];
            float ba = vb0[dx], bb = vb1[dx];
            acc0[0] += p4.x * (wa[1 + dx] + ba);
            acc0[1] += p4.y * (wa[2 + dx] + ba);
            acc0[2] += p4.z * (wa[3 + dx] + ba);
            acc0[3] += p4.w * (wa[4 + dx] + ba);
            acc1[0] += p4.x * (wb[1 + dx] + bb);
            acc1[1] += p4.y * (wb[2 + dx] + bb);
            acc1[2] += p4.z * (wb[3 + dx] + bb);
            acc1[3] += p4.w * (wb[4 + dx] + bb);
        }
    }

    float* ag = agg + ((long)n << 18) + ((long)(g * 128 + c0) << 10) + y * 32 + x0;
#pragma unroll
    for (int i = 0; i < 4; ++i) atomicAdd(&ag[i], acc0[i]);
#pragma unroll
    for (int i = 0; i < 4; ++i) atomicAdd(&ag[1024 + i], acc1[i]);
}

// ---------------------------------------------------------------------------
// ws floats: qp[1048576]@0  kp[1048576]@1048576  vpad[1572864]@2097152
//            rel/attn[1843200]@3670016  agg[1048576]@5513216   (~26.3 MB)
// ---------------------------------------------------------------------------
extern "C" void kernel_launch(void* const* d_in, const int* in_sizes, int n_in,
                              void* d_out, int out_size, void* d_ws, size_t ws_size,
                              hipStream_t stream)
{
    const float* q    = (const float*)d_in[0];
    const float* k    = (const float*)d_in[1];
    const float* v    = (const float*)d_in[2];
    const float* Wq   = (const float*)d_in[3];
    const float* bq   = (const float*)d_in[4];
    const float* Wk   = (const float*)d_in[5];
    const float* bk   = (const float*)d_in[6];
    const float* Wv   = (const float*)d_in[7];
    const float* bv   = (const float*)d_in[8];
    const float* Wrel = (const float*)d_in[9];
    const float* brel = (const float*)d_in[10];
    const float* Vb   = (const float*)d_in[11];
    const float* Wfc  = (const float*)d_in[12];
    const float* bfc  = (const float*)d_in[13];
    float* out = (float*)d_out;

    float* ws   = (float*)d_ws;
    float* qp   = ws;
    float* kp   = ws + 1048576;
    float* vpad = ws + 2097152;     // [bz 8][128 ch][32 row][48 col]
    float* rel  = ws + 3670016;     // 8*225*1024, becomes attn in place
    float* agg  = ws + 5513216;     // [n][256][1024]

    dim3 blk(256);

    // zero: vpad (padding must be 0), agg (atomic target), out (split-K FC)
    hipMemsetAsync(vpad, 0, (size_t)1572864 * 4, stream);
    hipMemsetAsync(agg, 0, (size_t)1048576 * 4, stream);
    hipMemsetAsync(out, 0, (size_t)out_size * 4, stream);

    // fused QKV projections: 16*4*12 = 768 blocks (V -> padded layout)
    qkv_kernel<<<dim3(16, 4, 12), blk, 0, stream>>>(q, k, v, Wq, Wk, Wv,
                                                    bq, bk, bv, qp, kp, vpad);

    // rel logits: 16*4*8 = 512 blocks, direct store
    gemm_kernel<<<dim3(16, 4, 8), blk, 0, stream>>>(Wrel, qp, brel, rel,
        225, 128, 28800, 2, 131072, 230400, 225, 2, 0, 1, 0);

    // scores + softmax -> attn (in place over rel): 512 blocks
    scores_kernel<<<dim3(64, 8), blk, 0, stream>>>(qp, kp, rel);

    // PV gather + V_bias fold -> agg (atomic): 1024 blocks
    pv_kernel<<<dim3(32, 4, 8), blk, 0, stream>>>(vpad, rel, Vb, agg);

    // FC with interleaved [m][n][c] store, split-K=2: 16*4*8 = 512 blocks
    gemm_kernel<<<dim3(16, 4, 8), blk, 0, stream>>>(Wfc, agg, bfc, out,
        256, 256, 0, 1, 262144, 0, 0, 1, 6, 2, 1024);
}